// Round 9
// baseline (212.338 us; speedup 1.0000x reference)
//
#include <hip/hip_runtime.h>

// Fused deformable-conv net — r19: 192-thread (3-wave) main blocks with
// ZERO idle lanes, one image per block, cells 0-191; the 4 leftover
// cells per image (2% of work) go to 86 cleanup blocks in the SAME grid
// (branch on blockIdx) using bounds-checked global gathers (r15: ~53%
// busy — fine for 2%, and concurrent, not serialized).
// Ledger constraints all preserved: LDS gathers on the 98% path (r15),
// frozen 64-VGPR r10 body verbatim, straight-line once per thread
// (r14/r16), 4-way position ILP (r17), one image per block (r13/r18b:
// multi-image or 7-wave blocks drop busy to 69-70%).
// r18b post-mortem: issue fell 10% as predicted but 7-wave blocks pack
// 28/32 waves per CU and park more per barrier -> busy 95->70. 3-wave
// blocks pack 10/CU (30 waves) with the finest barrier granularity yet.
// Epilogue: memset + atomicAdd from both paths (r13-proven), main block
// folds b_fc (exactly one per image).

#define NPOS  784
#define NPOOL 1568
#define CELLS 196
#define MAINC 192          // cells handled by the image's main block
#define TPB   192
#define WP    30
#define PIMG  900
#define CLIMG 48           // images per cleanup block (192 thr / 4 cells)

__device__ __forceinline__ float sample_unpadded(
    const float* __restrict__ xb, int ix, int iy)
{
    unsigned ux = (unsigned)(ix - 1), uy = (unsigned)(iy - 1);
    return (ux <= 27u && uy <= 27u) ? xb[ux * 28u + uy] : 0.f;
}

__global__ __launch_bounds__(192) void deform_net_kernel(
    const float* __restrict__ x,       // (B,1,28,28)
    const float* __restrict__ w_off,   // (18,1,3,3)
    const float* __restrict__ b_off,   // (18,)
    const float* __restrict__ w_conv,  // (8,1,3,3)
    const float* __restrict__ w_fc,    // (10,1568)
    const float* __restrict__ b_fc,    // (10,)
    float* __restrict__ out,           // (B,10), pre-zeroed
    int Btot)
{
    __shared__ float xs[PIMG];         // one zero-padded 30x30 image
    __shared__ float wo_s[162];
    __shared__ float bo_s[18];
    __shared__ float wc_s[72];
    __shared__ float red[3][10];

    const int tid = threadIdx.x;
    const int bid = blockIdx.x;
    const bool mainBlk = (bid < Btot);

    if (tid < 162) wo_s[tid] = w_off[tid];
    if (tid < 18)  bo_s[tid] = b_off[tid];
    if (tid < 72)  wc_s[tid] = w_conv[tid];

    if (mainBlk) {
        // Stage zero-padded image into LDS.
        const float* __restrict__ xb = x + (size_t)bid * NPOS;
        for (int i = tid; i < PIMG; i += TPB) {
            int r = i / WP, c = i - r * WP;
            float v = 0.f;
            if (r >= 1 && r <= 28 && c >= 1 && c <= 28)
                v = xb[(r - 1) * 28 + (c - 1)];
            xs[i] = v;
        }
    }
    __syncthreads();

    if (mainBlk) {
        // ================= MAIN PATH: cells 0..191, all lanes live ====
        const int cell = tid;
        const int ph = cell / 14, pw = cell - (cell / 14) * 14;
        const int h0 = 2 * ph, w0 = 2 * pw;

        float fc[10];
        #pragma unroll
        for (int c = 0; c < 10; c++) fc[c] = 0.f;

        // 4x4 padded-image neighborhood covering all 4 positions' taps.
        float nb[16];
        #pragma unroll
        for (int i = 0; i < 4; i++)
            #pragma unroll
            for (int j = 0; j < 4; j++)
                nb[i * 4 + j] = xs[(h0 + i) * WP + (w0 + j)];

        // ---- r10 champion body, FROZEN (k-outer, acc[4][8]) ----
        float acc[4][8];
        #pragma unroll
        for (int p = 0; p < 4; p++)
            #pragma unroll
            for (int o = 0; o < 8; o++) acc[p][o] = 0.f;

        #pragma unroll
        for (int k = 0; k < 9; k++) {          // deform tap
            const int kx = k / 3, ky = k % 3;
            #pragma unroll
            for (int p = 0; p < 4; p++) {      // position within pool cell
                const int dh = p >> 1, dw = p & 1;

                float offx = bo_s[k], offy = bo_s[k + 9];
                #pragma unroll
                for (int t = 0; t < 9; t++) {
                    float nv = nb[(dh + t / 3) * 4 + (dw + t % 3)];
                    offx = fmaf(wo_s[k * 9 + t],       nv, offx);
                    offy = fmaf(wo_s[(k + 9) * 9 + t], nv, offy);
                }

                float p_x = (float)(h0 + dh + kx) + offx;
                float p_y = (float)(w0 + dw + ky) + offy;

                float q0x = floorf(p_x), q0y = floorf(p_y);
                float qltx = __builtin_amdgcn_fmed3f(q0x,       0.f, 29.f);
                float qlty = __builtin_amdgcn_fmed3f(q0y,       0.f, 29.f);
                float qrbx = __builtin_amdgcn_fmed3f(q0x + 1.f, 0.f, 29.f);
                float qrby = __builtin_amdgcn_fmed3f(q0y + 1.f, 0.f, 29.f);
                float px   = __builtin_amdgcn_fmed3f(p_x,       0.f, 29.f);
                float py   = __builtin_amdgcn_fmed3f(p_y,       0.f, 29.f);

                float gltx = 1.f + (qltx - px);
                float glty = 1.f + (qlty - py);
                float grbx = 1.f - (qrbx - px);
                float grby = 1.f - (qrby - py);

                int ilx = (int)qltx, ily = (int)qlty;
                int irx = (int)qrbx, iry = (int)qrby;

                float xlt = xs[ilx * WP + ily];
                float xrb = xs[irx * WP + iry];
                float xlb = xs[ilx * WP + iry];
                float xrt = xs[irx * WP + ily];

                float s = gltx * (glty * xlt + grby * xlb)
                        + grbx * (glty * xrt + grby * xrb);

                #pragma unroll
                for (int o = 0; o < 8; o++)
                    acc[p][o] = fmaf(wc_s[o * 9 + k], s, acc[p][o]);
            }
        }

        // relu + 2x2 maxpool in registers, then FC partials (o-outer).
        #pragma unroll
        for (int o = 0; o < 8; o++) {
            float m = fmaxf(fmaxf(acc[0][o], acc[1][o]),
                            fmaxf(acc[2][o], acc[3][o]));
            m = fmaxf(m, 0.f);
            const float* wrow = w_fc + o * CELLS + cell;
            #pragma unroll
            for (int c = 0; c < 10; c++)
                fc[c] = fmaf(m, wrow[c * NPOOL], fc[c]);
        }
        // ---- end frozen body ----

        // 3 full waves: butterfly reduce, cross-wave via LDS.
        #pragma unroll
        for (int c = 0; c < 10; c++) {
            #pragma unroll
            for (int sh = 32; sh > 0; sh >>= 1)
                fc[c] += __shfl_down(fc[c], sh, 64);
        }
        const int wave = tid >> 6, lane = tid & 63;
        if (lane == 0) {
            #pragma unroll
            for (int c = 0; c < 10; c++) red[wave][c] = fc[c];
        }
        __syncthreads();
        if (tid < 10)
            atomicAdd(out + bid * 10 + tid,
                      red[0][tid] + red[1][tid] + red[2][tid] + b_fc[tid]);
    } else {
        // ============ CLEANUP PATH: cells 192..195 for 48 images ======
        const int cb   = bid - Btot;
        const int img  = cb * CLIMG + (tid >> 2);
        const int cell = MAINC + (tid & 3);          // 192..195

        float fc[10];
        #pragma unroll
        for (int c = 0; c < 10; c++) fc[c] = 0.f;

        if (img < Btot) {
            const float* __restrict__ xb = x + (size_t)img * NPOS;
            const int ph = cell / 14, pw = cell - (cell / 14) * 14;
            const int h0 = 2 * ph, w0 = 2 * pw;

            float nb[16];
            #pragma unroll
            for (int i = 0; i < 4; i++)
                #pragma unroll
                for (int j = 0; j < 4; j++)
                    nb[i * 4 + j] = sample_unpadded(xb, h0 + i, w0 + j);

            float acc[4][8];
            #pragma unroll
            for (int p = 0; p < 4; p++)
                #pragma unroll
                for (int o = 0; o < 8; o++) acc[p][o] = 0.f;

            #pragma unroll
            for (int k = 0; k < 9; k++) {
                const int kx = k / 3, ky = k % 3;
                #pragma unroll
                for (int p = 0; p < 4; p++) {
                    const int dh = p >> 1, dw = p & 1;

                    float offx = bo_s[k], offy = bo_s[k + 9];
                    #pragma unroll
                    for (int t = 0; t < 9; t++) {
                        float nv = nb[(dh + t / 3) * 4 + (dw + t % 3)];
                        offx = fmaf(wo_s[k * 9 + t],       nv, offx);
                        offy = fmaf(wo_s[(k + 9) * 9 + t], nv, offy);
                    }

                    float p_x = (float)(h0 + dh + kx) + offx;
                    float p_y = (float)(w0 + dw + ky) + offy;

                    float q0x = floorf(p_x), q0y = floorf(p_y);
                    float qltx = __builtin_amdgcn_fmed3f(q0x,       0.f, 29.f);
                    float qlty = __builtin_amdgcn_fmed3f(q0y,       0.f, 29.f);
                    float qrbx = __builtin_amdgcn_fmed3f(q0x + 1.f, 0.f, 29.f);
                    float qrby = __builtin_amdgcn_fmed3f(q0y + 1.f, 0.f, 29.f);
                    float px   = __builtin_amdgcn_fmed3f(p_x,       0.f, 29.f);
                    float py   = __builtin_amdgcn_fmed3f(p_y,       0.f, 29.f);

                    float gltx = 1.f + (qltx - px);
                    float glty = 1.f + (qlty - py);
                    float grbx = 1.f - (qrbx - px);
                    float grby = 1.f - (qrby - py);

                    int ilx = (int)qltx, ily = (int)qlty;
                    int irx = (int)qrbx, iry = (int)qrby;

                    // padded-frame [0,29] -> unpadded with bounds check
                    float xlt = sample_unpadded(xb, ilx, ily);
                    float xrb = sample_unpadded(xb, irx, iry);
                    float xlb = sample_unpadded(xb, ilx, iry);
                    float xrt = sample_unpadded(xb, irx, ily);

                    float s = gltx * (glty * xlt + grby * xlb)
                            + grbx * (glty * xrt + grby * xrb);

                    #pragma unroll
                    for (int o = 0; o < 8; o++)
                        acc[p][o] = fmaf(wc_s[o * 9 + k], s, acc[p][o]);
                }
            }

            #pragma unroll
            for (int o = 0; o < 8; o++) {
                float m = fmaxf(fmaxf(acc[0][o], acc[1][o]),
                                fmaxf(acc[2][o], acc[3][o]));
                m = fmaxf(m, 0.f);
                const float* wrow = w_fc + o * CELLS + cell;
                #pragma unroll
                for (int c = 0; c < 10; c++)
                    fc[c] = fmaf(m, wrow[c * NPOOL], fc[c]);
            }
        }

        // Sum the 4 cells of each image (4-lane groups), one adder lane.
        #pragma unroll
        for (int c = 0; c < 10; c++) {
            fc[c] += __shfl_xor(fc[c], 1, 64);
            fc[c] += __shfl_xor(fc[c], 2, 64);
        }
        if ((tid & 3) == 0 && img < Btot) {
            #pragma unroll
            for (int c = 0; c < 10; c++)
                atomicAdd(out + img * 10 + c, fc[c]);
        }
    }
}

extern "C" void kernel_launch(void* const* d_in, const int* in_sizes, int n_in,
                              void* d_out, int out_size, void* d_ws, size_t ws_size,
                              hipStream_t stream) {
    const float* x      = (const float*)d_in[0];
    const float* w_off  = (const float*)d_in[1];
    const float* b_off  = (const float*)d_in[2];
    const float* w_conv = (const float*)d_in[3];
    const float* w_fc   = (const float*)d_in[4];
    const float* b_fc   = (const float*)d_in[5];
    float* out = (float*)d_out;

    const int B = in_sizes[0] / NPOS;
    hipMemsetAsync(d_out, 0, (size_t)B * 10 * sizeof(float), stream);
    const int nclean = (B + CLIMG - 1) / CLIMG;     // 86 for B=4096
    deform_net_kernel<<<B + nclean, TPB, 0, stream>>>(
        x, w_off, b_off, w_conv, w_fc, b_fc, out, B);
}

// Round 10
// 129.326 us; speedup vs baseline: 1.6419x; 1.6419x over previous
//
#include <hip/hip_runtime.h>

// Fused deformable-conv net — r20: r19's 3-wave-block design with the
// two paths split into SEPARATE KERNELS (r19 post-mortem: fusing the
// LDS-main and global-gather-cleanup paths into one kernel made the
// allocator provision max(both bodies) = 232 VGPR, 23% busy — the
// r14/r16 failure class. The 3-wave shape itself was never measured).
//  - main kernel: 192 thr (3 FULL waves), one image/block, cells 0-191.
//    This is r10 champion with the if(tid<196) guard REMOVED: same
//    frozen 64-VGPR body, same LDS gathers, 3 wave-body-passes/image
//    vs r10's 4 (-25% issue), 10 blocks/CU (30 waves).
//  - tail kernel (runs FIRST, 86 blocks): cells 192-195 for 48
//    images/block, bounds-checked global gathers (2% of work; separate
//    compilation so its VGPR count is irrelevant). Direct store.
// No atomics, no memset: tail direct-stores every image's partial;
// main (same stream, after) does out += sums + b_fc non-atomically.
// Ledger constraints preserved: LDS gathers (r15), straight-line body
// once per thread (r14/r16), 4-way position ILP (r17), one image per
// block (r13/r18b), frozen body verbatim.

#define NPOS  784
#define NPOOL 1568
#define CELLS 196
#define MAINC 192
#define TPB   192
#define WP    30
#define PIMG  900
#define CLIMG 48           // images per tail block (192 thr / 4 cells)

__device__ __forceinline__ float sample_unpadded(
    const float* __restrict__ xb, int ix, int iy)
{
    unsigned ux = (unsigned)(ix - 1), uy = (unsigned)(iy - 1);
    return (ux <= 27u && uy <= 27u) ? xb[ux * 28u + uy] : 0.f;
}

// ---------- tail: cells 192..195 of every image, direct store ----------
__global__ __launch_bounds__(192) void deform_tail_kernel(
    const float* __restrict__ x,
    const float* __restrict__ w_off,
    const float* __restrict__ b_off,
    const float* __restrict__ w_conv,
    const float* __restrict__ w_fc,
    float* __restrict__ out,
    int Btot)
{
    __shared__ float wo_s[162];
    __shared__ float bo_s[18];
    __shared__ float wc_s[72];

    const int tid = threadIdx.x;
    if (tid < 162) wo_s[tid] = w_off[tid];
    if (tid < 18)  bo_s[tid] = b_off[tid];
    if (tid < 72)  wc_s[tid] = w_conv[tid];
    __syncthreads();

    const int img  = blockIdx.x * CLIMG + (tid >> 2);
    const int cell = MAINC + (tid & 3);              // 192..195

    float fc[10];
    #pragma unroll
    for (int c = 0; c < 10; c++) fc[c] = 0.f;

    if (img < Btot) {
        const float* __restrict__ xb = x + (size_t)img * NPOS;
        const int ph = cell / 14, pw = cell - (cell / 14) * 14;
        const int h0 = 2 * ph, w0 = 2 * pw;

        float nb[16];
        #pragma unroll
        for (int i = 0; i < 4; i++)
            #pragma unroll
            for (int j = 0; j < 4; j++)
                nb[i * 4 + j] = sample_unpadded(xb, h0 + i, w0 + j);

        float acc[4][8];
        #pragma unroll
        for (int p = 0; p < 4; p++)
            #pragma unroll
            for (int o = 0; o < 8; o++) acc[p][o] = 0.f;

        #pragma unroll
        for (int k = 0; k < 9; k++) {
            const int kx = k / 3, ky = k % 3;
            #pragma unroll
            for (int p = 0; p < 4; p++) {
                const int dh = p >> 1, dw = p & 1;

                float offx = bo_s[k], offy = bo_s[k + 9];
                #pragma unroll
                for (int t = 0; t < 9; t++) {
                    float nv = nb[(dh + t / 3) * 4 + (dw + t % 3)];
                    offx = fmaf(wo_s[k * 9 + t],       nv, offx);
                    offy = fmaf(wo_s[(k + 9) * 9 + t], nv, offy);
                }

                float p_x = (float)(h0 + dh + kx) + offx;
                float p_y = (float)(w0 + dw + ky) + offy;

                float q0x = floorf(p_x), q0y = floorf(p_y);
                float qltx = __builtin_amdgcn_fmed3f(q0x,       0.f, 29.f);
                float qlty = __builtin_amdgcn_fmed3f(q0y,       0.f, 29.f);
                float qrbx = __builtin_amdgcn_fmed3f(q0x + 1.f, 0.f, 29.f);
                float qrby = __builtin_amdgcn_fmed3f(q0y + 1.f, 0.f, 29.f);
                float px   = __builtin_amdgcn_fmed3f(p_x,       0.f, 29.f);
                float py   = __builtin_amdgcn_fmed3f(p_y,       0.f, 29.f);

                float gltx = 1.f + (qltx - px);
                float glty = 1.f + (qlty - py);
                float grbx = 1.f - (qrbx - px);
                float grby = 1.f - (qrby - py);

                int ilx = (int)qltx, ily = (int)qlty;
                int irx = (int)qrbx, iry = (int)qrby;

                float xlt = sample_unpadded(xb, ilx, ily);
                float xrb = sample_unpadded(xb, irx, iry);
                float xlb = sample_unpadded(xb, ilx, iry);
                float xrt = sample_unpadded(xb, irx, ily);

                float s = gltx * (glty * xlt + grby * xlb)
                        + grbx * (glty * xrt + grby * xrb);

                #pragma unroll
                for (int o = 0; o < 8; o++)
                    acc[p][o] = fmaf(wc_s[o * 9 + k], s, acc[p][o]);
            }
        }

        #pragma unroll
        for (int o = 0; o < 8; o++) {
            float m = fmaxf(fmaxf(acc[0][o], acc[1][o]),
                            fmaxf(acc[2][o], acc[3][o]));
            m = fmaxf(m, 0.f);
            const float* wrow = w_fc + o * CELLS + cell;
            #pragma unroll
            for (int c = 0; c < 10; c++)
                fc[c] = fmaf(m, wrow[c * NPOOL], fc[c]);
        }
    }

    // Sum the 4 cells of each image (4-lane groups); one lane stores.
    #pragma unroll
    for (int c = 0; c < 10; c++) {
        fc[c] += __shfl_xor(fc[c], 1, 64);
        fc[c] += __shfl_xor(fc[c], 2, 64);
    }
    if ((tid & 3) == 0 && img < Btot) {
        #pragma unroll
        for (int c = 0; c < 10; c++)
            out[img * 10 + c] = fc[c];       // direct store (unique owner)
    }
}

// ---------- main: cells 0..191, one image per 3-wave block ----------
__global__ __launch_bounds__(192) void deform_net_kernel(
    const float* __restrict__ x,       // (B,1,28,28)
    const float* __restrict__ w_off,   // (18,1,3,3)
    const float* __restrict__ b_off,   // (18,)
    const float* __restrict__ w_conv,  // (8,1,3,3)
    const float* __restrict__ w_fc,    // (10,1568)
    const float* __restrict__ b_fc,    // (10,)
    float* __restrict__ out)           // (B,10), tail partials present
{
    __shared__ float xs[PIMG];         // one zero-padded 30x30 image
    __shared__ float wo_s[162];
    __shared__ float bo_s[18];
    __shared__ float wc_s[72];
    __shared__ float red[3][10];

    const int tid = threadIdx.x;
    const int b   = blockIdx.x;

    if (tid < 162) wo_s[tid] = w_off[tid];
    if (tid < 18)  bo_s[tid] = b_off[tid];
    if (tid < 72)  wc_s[tid] = w_conv[tid];

    // Stage zero-padded image into LDS.
    const float* __restrict__ xb = x + (size_t)b * NPOS;
    for (int i = tid; i < PIMG; i += TPB) {
        int r = i / WP, c = i - r * WP;
        float v = 0.f;
        if (r >= 1 && r <= 28 && c >= 1 && c <= 28)
            v = xb[(r - 1) * 28 + (c - 1)];
        xs[i] = v;
    }
    __syncthreads();

    const int cell = tid;              // 0..191, every lane live
    const int ph = cell / 14, pw = cell - (cell / 14) * 14;
    const int h0 = 2 * ph, w0 = 2 * pw;

    float fc[10];
    #pragma unroll
    for (int c = 0; c < 10; c++) fc[c] = 0.f;

    // 4x4 padded-image neighborhood covering all 4 positions' 3x3 taps.
    float nb[16];
    #pragma unroll
    for (int i = 0; i < 4; i++)
        #pragma unroll
        for (int j = 0; j < 4; j++)
            nb[i * 4 + j] = xs[(h0 + i) * WP + (w0 + j)];

    // ---- r10 champion body, FROZEN (k-outer, acc[4][8]) ----
    float acc[4][8];
    #pragma unroll
    for (int p = 0; p < 4; p++)
        #pragma unroll
        for (int o = 0; o < 8; o++) acc[p][o] = 0.f;

    #pragma unroll
    for (int k = 0; k < 9; k++) {          // deform tap
        const int kx = k / 3, ky = k % 3;
        #pragma unroll
        for (int p = 0; p < 4; p++) {      // position within pool cell
            const int dh = p >> 1, dw = p & 1;

            float offx = bo_s[k], offy = bo_s[k + 9];
            #pragma unroll
            for (int t = 0; t < 9; t++) {
                float nv = nb[(dh + t / 3) * 4 + (dw + t % 3)];
                offx = fmaf(wo_s[k * 9 + t],       nv, offx);
                offy = fmaf(wo_s[(k + 9) * 9 + t], nv, offy);
            }

            float p_x = (float)(h0 + dh + kx) + offx;
            float p_y = (float)(w0 + dw + ky) + offy;

            float q0x = floorf(p_x), q0y = floorf(p_y);
            float qltx = __builtin_amdgcn_fmed3f(q0x,       0.f, 29.f);
            float qlty = __builtin_amdgcn_fmed3f(q0y,       0.f, 29.f);
            float qrbx = __builtin_amdgcn_fmed3f(q0x + 1.f, 0.f, 29.f);
            float qrby = __builtin_amdgcn_fmed3f(q0y + 1.f, 0.f, 29.f);
            float px   = __builtin_amdgcn_fmed3f(p_x,       0.f, 29.f);
            float py   = __builtin_amdgcn_fmed3f(p_y,       0.f, 29.f);

            float gltx = 1.f + (qltx - px);
            float glty = 1.f + (qlty - py);
            float grbx = 1.f - (qrbx - px);
            float grby = 1.f - (qrby - py);

            int ilx = (int)qltx, ily = (int)qlty;
            int irx = (int)qrbx, iry = (int)qrby;

            float xlt = xs[ilx * WP + ily];
            float xrb = xs[irx * WP + iry];
            float xlb = xs[ilx * WP + iry];
            float xrt = xs[irx * WP + ily];

            float s = gltx * (glty * xlt + grby * xlb)
                    + grbx * (glty * xrt + grby * xrb);

            #pragma unroll
            for (int o = 0; o < 8; o++)
                acc[p][o] = fmaf(wc_s[o * 9 + k], s, acc[p][o]);
        }
    }

    // relu + 2x2 maxpool in registers, then FC partials (o-outer).
    #pragma unroll
    for (int o = 0; o < 8; o++) {
        float m = fmaxf(fmaxf(acc[0][o], acc[1][o]),
                        fmaxf(acc[2][o], acc[3][o]));
        m = fmaxf(m, 0.f);
        const float* wrow = w_fc + o * CELLS + cell;
        #pragma unroll
        for (int c = 0; c < 10; c++)
            fc[c] = fmaf(m, wrow[c * NPOOL], fc[c]);
    }
    // ---- end frozen body ----

    // 3 full waves: butterfly reduce, cross-wave via LDS.
    #pragma unroll
    for (int c = 0; c < 10; c++) {
        #pragma unroll
        for (int sh = 32; sh > 0; sh >>= 1)
            fc[c] += __shfl_down(fc[c], sh, 64);
    }
    const int wave = tid >> 6, lane = tid & 63;
    if (lane == 0) {
        #pragma unroll
        for (int c = 0; c < 10; c++) red[wave][c] = fc[c];
    }
    __syncthreads();

    // Accumulate onto the tail partial (stream order guarantees it's
    // there); exactly one writer per output element -> non-atomic.
    if (tid < 10)
        out[b * 10 + tid] += red[0][tid] + red[1][tid] + red[2][tid]
                           + b_fc[tid];
}

extern "C" void kernel_launch(void* const* d_in, const int* in_sizes, int n_in,
                              void* d_out, int out_size, void* d_ws, size_t ws_size,
                              hipStream_t stream) {
    const float* x      = (const float*)d_in[0];
    const float* w_off  = (const float*)d_in[1];
    const float* b_off  = (const float*)d_in[2];
    const float* w_conv = (const float*)d_in[3];
    const float* w_fc   = (const float*)d_in[4];
    const float* b_fc   = (const float*)d_in[5];
    float* out = (float*)d_out;

    const int B = in_sizes[0] / NPOS;
    const int ntail = (B + CLIMG - 1) / CLIMG;      // 86 for B=4096
    deform_tail_kernel<<<ntail, TPB, 0, stream>>>(
        x, w_off, b_off, w_conv, w_fc, out, B);
    deform_net_kernel<<<B, TPB, 0, stream>>>(
        x, w_off, b_off, w_conv, w_fc, b_fc, out);
}